// Round 1
// baseline (125.933 us; speedup 1.0000x reference)
//
#include <hip/hip_runtime.h>

#define DIMX 100
#define ROWS 64          // rows per block
#define KSTR 136         // u16 k-stride (128 pad + 8 -> 2-way-free b128 reads)
#define NPAD 112         // padded N (7 tiles of 16)
#define BSTR 116         // u16 stride for base tile

typedef __bf16 bf16x8 __attribute__((ext_vector_type(8)));
typedef float  f32x4  __attribute__((ext_vector_type(4)));

static __device__ inline unsigned short f2bf(float f) {
    unsigned int u = __builtin_bit_cast(unsigned int, f);
    u += 0x7FFFu + ((u >> 16) & 1u);        // round-to-nearest-even
    return (unsigned short)(u >> 16);
}

__global__ __launch_bounds__(256, 2) void ca_fused(
    const float* __restrict__ state, const float* __restrict__ Amat,
    const float* __restrict__ target, float* __restrict__ out)
{
    __shared__ __align__(16) unsigned short sS[ROWS * KSTR];    // s (bf16) [row][k]
    __shared__ __align__(16) unsigned short sB[NPAD * KSTR];    // A as B-operand: [j][k] (bf16)
    __shared__ __align__(16) unsigned short sBase[ROWS * BSTR]; // -x + u*s (bf16) [row][j]

    const int tid = threadIdx.x;
    const long r0 = (long)blockIdx.x * ROWS;

    // ---- zero-init LDS (pads MUST be 0: 0*garbage in MFMA K-pad, avoid NaN) ----
    for (int i = tid; i < (ROWS * KSTR) / 2; i += 256)
        reinterpret_cast<unsigned int*>(sS)[i] = 0u;
    for (int i = tid; i < (NPAD * KSTR) / 2; i += 256)
        reinterpret_cast<unsigned int*>(sB)[i] = 0u;

    // ---- zeros half of output: cols 200..399, float4 stores ----
    for (int i = tid; i < ROWS * 50; i += 256) {
        int r = i / 50, c4 = i - r * 50;
        *reinterpret_cast<f32x4*>(&out[(r0 + r) * 400 + 200 + c4 * 4]) =
            f32x4{0.f, 0.f, 0.f, 0.f};
    }
    __syncthreads();

    // ---- stage A[j][k] -> sB (bf16), coalesced global reads ----
    for (int i = tid; i < DIMX * DIMX; i += 256) {
        int j = i / DIMX, k = i - j * DIMX;
        sB[j * KSTR + k] = f2bf(Amat[i]);
    }

    // ---- stage state -> s (bf16) and base = -x + u*s (bf16), fp32 math ----
    for (int i = tid; i < ROWS * DIMX; i += 256) {
        int r = i / DIMX, c = i - r * DIMX;
        long ro = (r0 + r) * 400;
        float x = state[ro + c];
        float e = state[ro + DIMX + c];
        float w = state[ro + 3 * DIMX + c];
        float u = w * (x + e - target[c]);
        float x2 = x * x;
        float s = x2 / (1.0f + x2);
        sS[r * KSTR + c] = f2bf(s);
        sBase[r * BSTR + c] = f2bf(fmaf(u, s, -x));
    }
    __syncthreads();

    // ---- MFMA: each wave owns one 16-row M-tile ----
    const int wave = tid >> 6, lane = tid & 63;
    const int fr = lane & 15;            // M/N index within fragment
    const int kk = (lane >> 4) * 8;      // K offset within 32-chunk
    const int mbase = wave * 16;

    bf16x8 afrag[4];
#pragma unroll
    for (int kt = 0; kt < 4; ++kt)
        afrag[kt] = *reinterpret_cast<const bf16x8*>(
            &sS[(mbase + fr) * KSTR + kt * 32 + kk]);

    for (int n = 0; n < 7; ++n) {
        f32x4 acc = {0.f, 0.f, 0.f, 0.f};
#pragma unroll
        for (int kt = 0; kt < 4; ++kt) {
            bf16x8 bfrag = *reinterpret_cast<const bf16x8*>(
                &sB[(n * 16 + fr) * KSTR + kt * 32 + kk]);
            acc = __builtin_amdgcn_mfma_f32_16x16x32_bf16(afrag[kt], bfrag, acc, 0, 0, 0);
        }
        int j = n * 16 + fr;             // C/D: col = lane&15
        if (j < DIMX) {
#pragma unroll
            for (int q = 0; q < 4; ++q) {
                int row = mbase + (lane >> 4) * 4 + q;   // C/D: row = (lane>>4)*4 + reg
                unsigned int ub = ((unsigned int)sBase[row * BSTR + j]) << 16;
                float v = acc[q] + __builtin_bit_cast(float, ub);
                long o = (r0 + row) * 400 + j;
                out[o] = v;
                out[o + DIMX] = -v;
            }
        }
    }
}

extern "C" void kernel_launch(void* const* d_in, const int* in_sizes, int n_in,
                              void* d_out, int out_size, void* d_ws, size_t ws_size,
                              hipStream_t stream) {
    const float* state  = (const float*)d_in[0];
    const float* Amat   = (const float*)d_in[1];
    const float* target = (const float*)d_in[2];
    float* out = (float*)d_out;
    (void)in_sizes; (void)n_in; (void)out_size; (void)d_ws; (void)ws_size;
    ca_fused<<<dim3(131072 / ROWS), dim3(256), 0, stream>>>(state, Amat, target, out);
}

// Round 2
// 115.835 us; speedup vs baseline: 1.0872x; 1.0872x over previous
//
#include <hip/hip_runtime.h>

#define DIMX 100
#define BATCH 131072

typedef __bf16 bf16x8 __attribute__((ext_vector_type(8)));
typedef float  f32x4  __attribute__((ext_vector_type(4)));

// ---- kernel 1: convert A (100x100 fp32, row-major) to zero-padded bf16 [112][128] in ws ----
__global__ void conv_A(const float* __restrict__ A, __bf16* __restrict__ ws) {
    int i = blockIdx.x * 256 + threadIdx.x;          // 112*128 = 14336
    if (i < 112 * 128) {
        int j = i >> 7, k = i & 127;
        float v = (j < DIMX && k < DIMX) ? A[j * DIMX + k] : 0.0f;
        ws[i] = (__bf16)v;
    }
}

// ---- main kernel: no LDS, no barriers; each wave owns 16 rows ----
template <bool USE_WS>
__global__ __launch_bounds__(256) void ca_main(
    const float* __restrict__ state, const float* __restrict__ Amat,
    const __bf16* __restrict__ Bws, const float* __restrict__ target,
    float* __restrict__ out)
{
    const int tid  = threadIdx.x;
    const int wave = tid >> 6, lane = tid & 63;
    const int fr = lane & 15;          // fragment row/col index
    const int h  = lane >> 4;          // k-group / acc row group
    const long r0 = (long)blockIdx.x * 64 + wave * 16;   // wave's first row

    // ---- zeros half of output: cols 200..399 for the wave's 16 rows ----
#pragma unroll
    for (int it = 0; it < 13; ++it) {
        int i = lane + it * 64;
        if (i < 800) {
            int r = i / 50, c4 = i - r * 50;
            *reinterpret_cast<f32x4*>(&out[(r0 + r) * 400 + 200 + c4 * 4]) =
                f32x4{0.f, 0.f, 0.f, 0.f};
        }
    }

    // ---- A-operand frags: s = x^2/(1+x^2), built in-register from global x ----
    const float* sp = state + (r0 + fr) * 400;
    bf16x8 afrag[4];
#pragma unroll
    for (int kt = 0; kt < 4; ++kt) {
        int k0 = kt * 32 + h * 8;
        bf16x8 f = {};
        if (k0 < DIMX) {                       // kt=3,h>=1 -> all-zero frag
            f32x4 xa = *reinterpret_cast<const f32x4*>(sp + k0);
            f32x4 xb = *reinterpret_cast<const f32x4*>(sp + k0 + 4);
#pragma unroll
            for (int e = 0; e < 8; ++e) {
                float x = (e < 4) ? xa[e] : xb[e - 4];
                float x2 = x * x;
                float s = x2 * __builtin_amdgcn_rcpf(1.0f + x2);
                f[e] = (k0 + e < DIMX) ? (__bf16)s : (__bf16)0.0f;
            }
        }
        afrag[kt] = f;
    }

    // ---- base = -x + u*s for this lane's 28 (row,j) output elements (fp32) ----
    // C/D layout: j = n*16 + fr, row = h*4 + q
    float basev[7][4];
#pragma unroll
    for (int n = 0; n < 7; ++n) {
        int j = n * 16 + fr;
        bool jv = (j < DIMX);
        float tj = jv ? target[j] : 0.0f;
#pragma unroll
        for (int q = 0; q < 4; ++q) {
            const float* rp = state + (r0 + h * 4 + q) * 400;
            float x = jv ? rp[j] : 0.0f;
            float e = jv ? rp[j + DIMX] : 0.0f;
            float w = jv ? rp[j + 3 * DIMX] : 0.0f;
            float u = w * (x + e - tj);
            float x2 = x * x;
            float s = x2 * __builtin_amdgcn_rcpf(1.0f + x2);
            basev[n][q] = fmaf(u, s, -x);
        }
    }

    // ---- MFMA over 7 N-tiles ----
#pragma unroll
    for (int n = 0; n < 7; ++n) {
        f32x4 acc = {0.f, 0.f, 0.f, 0.f};
#pragma unroll
        for (int kt = 0; kt < 4; ++kt) {
            bf16x8 bf;
            if constexpr (USE_WS) {
                bf = *reinterpret_cast<const bf16x8*>(
                    Bws + (n * 16 + fr) * 128 + kt * 32 + h * 8);
            } else {
                int jj = n * 16 + fr;
#pragma unroll
                for (int e = 0; e < 8; ++e) {
                    int k = kt * 32 + h * 8 + e;
                    float v = (jj < DIMX && k < DIMX) ? Amat[jj * DIMX + k] : 0.0f;
                    bf[e] = (__bf16)v;
                }
            }
            acc = __builtin_amdgcn_mfma_f32_16x16x32_bf16(afrag[kt], bf, acc, 0, 0, 0);
        }
        int j = n * 16 + fr;
        if (j < DIMX) {
#pragma unroll
            for (int q = 0; q < 4; ++q) {
                float v = acc[q] + basev[n][q];
                float* op = out + (r0 + h * 4 + q) * 400 + j;
                op[0] = v;
                op[DIMX] = -v;
            }
        }
    }
}

extern "C" void kernel_launch(void* const* d_in, const int* in_sizes, int n_in,
                              void* d_out, int out_size, void* d_ws, size_t ws_size,
                              hipStream_t stream) {
    const float* state  = (const float*)d_in[0];
    const float* Amat   = (const float*)d_in[1];
    const float* target = (const float*)d_in[2];
    float* out = (float*)d_out;
    (void)in_sizes; (void)n_in; (void)out_size;

    if (ws_size >= (size_t)(112 * 128 * sizeof(__bf16))) {
        conv_A<<<dim3(56), dim3(256), 0, stream>>>(Amat, (__bf16*)d_ws);
        ca_main<true><<<dim3(BATCH / 64), dim3(256), 0, stream>>>(
            state, Amat, (const __bf16*)d_ws, target, out);
    } else {
        ca_main<false><<<dim3(BATCH / 64), dim3(256), 0, stream>>>(
            state, Amat, nullptr, target, out);
    }
}

// Round 3
// 100.476 us; speedup vs baseline: 1.2534x; 1.1529x over previous
//
#include <hip/hip_runtime.h>

#define DIMX 100
#define BATCH 131072
#define RPB 64            // rows per block
#define BUFW 108          // f32 stride: 432 B = 16B-aligned; 432%128 -> 2-way-free banks

typedef __bf16 bf16x8 __attribute__((ext_vector_type(8)));
typedef float  f32x4  __attribute__((ext_vector_type(4)));

// ---- kernel 1: convert A (100x100 fp32) to zero-padded bf16 [112][128] in ws ----
__global__ void conv_A(const float* __restrict__ A, __bf16* __restrict__ ws) {
    int i = blockIdx.x * 256 + threadIdx.x;          // 112*128 = 14336
    if (i < 112 * 128) {
        int j = i >> 7, k = i & 127;
        float v = (j < DIMX && k < DIMX) ? A[j * DIMX + k] : 0.0f;
        ws[i] = (__bf16)v;
    }
}

template <bool USE_WS>
__global__ __launch_bounds__(256) void ca_main(
    const float* __restrict__ state, const float* __restrict__ Amat,
    const __bf16* __restrict__ Bws, const float* __restrict__ target,
    float* __restrict__ out)
{
    __shared__ __align__(16) float buf[RPB * BUFW];   // 27648 B -> 5 blocks/CU

    const int tid = threadIdx.x;
    const long r0 = (long)blockIdx.x * RPB;

    // ---- Phase A: coalesced float4 sweep; base = -x + u*s -> LDS ----
#pragma unroll
    for (int it = 0; it < 7; ++it) {
        int i = tid + it * 256;                       // RPB*25 = 1600
        if (i < RPB * 25) {
            int row = i / 25, c4 = i - row * 25;
            int j0 = c4 * 4;
            const float* rp = state + (r0 + row) * 400;
            f32x4 x = *reinterpret_cast<const f32x4*>(rp + j0);
            f32x4 e = *reinterpret_cast<const f32x4*>(rp + DIMX + j0);
            f32x4 w = *reinterpret_cast<const f32x4*>(rp + 3 * DIMX + j0);
            f32x4 t = *reinterpret_cast<const f32x4*>(target + j0);
            f32x4 b;
#pragma unroll
            for (int q = 0; q < 4; ++q) {
                float u  = w[q] * (x[q] + e[q] - t[q]);
                float x2 = x[q] * x[q];
                float s  = x2 * __builtin_amdgcn_rcpf(1.0f + x2);
                b[q] = fmaf(u, s, -x[q]);
            }
            *reinterpret_cast<f32x4*>(&buf[row * BUFW + j0]) = b;
        }
    }

    // ---- A-operand frags from global x (L1/L2-hot), s computed in-register ----
    const int wave = tid >> 6, lane = tid & 63;
    const int fr = lane & 15, h = lane >> 4;
    const float* sp = state + (r0 + wave * 16 + fr) * 400;
    bf16x8 afrag[4];
#pragma unroll
    for (int kt = 0; kt < 4; ++kt) {
        int k0 = kt * 32 + h * 8;
        bf16x8 f = {};
        if (k0 < DIMX) {
            f32x4 xa = *reinterpret_cast<const f32x4*>(sp + k0);
            f32x4 xb = *reinterpret_cast<const f32x4*>(sp + k0 + 4);
#pragma unroll
            for (int e = 0; e < 8; ++e) {
                float x = (e < 4) ? xa[e] : xb[e - 4];
                float x2 = x * x;
                float s = x2 * __builtin_amdgcn_rcpf(1.0f + x2);
                f[e] = (k0 + e < DIMX) ? (__bf16)s : (__bf16)0.0f;
            }
        }
        afrag[kt] = f;
    }

    __syncthreads();   // buf (phase A) complete

    // ---- MFMA over 7 N-tiles; epilogue: buf[row][j] += acc (2-way-free RMW) ----
#pragma unroll
    for (int n = 0; n < 7; ++n) {
        f32x4 acc = {0.f, 0.f, 0.f, 0.f};
#pragma unroll
        for (int kt = 0; kt < 4; ++kt) {
            bf16x8 bf;
            if constexpr (USE_WS) {
                bf = *reinterpret_cast<const bf16x8*>(
                    Bws + (n * 16 + fr) * 128 + kt * 32 + h * 8);
            } else {
                int jj = n * 16 + fr;
#pragma unroll
                for (int e = 0; e < 8; ++e) {
                    int k = kt * 32 + h * 8 + e;
                    float v = (jj < DIMX && k < DIMX) ? Amat[jj * DIMX + k] : 0.0f;
                    bf[e] = (__bf16)v;
                }
            }
            acc = __builtin_amdgcn_mfma_f32_16x16x32_bf16(afrag[kt], bf, acc, 0, 0, 0);
        }
        int j = n * 16 + fr;
        if (j < DIMX) {
#pragma unroll
            for (int q = 0; q < 4; ++q) {
                int row = wave * 16 + h * 4 + q;
                buf[row * BUFW + j] += acc[q];
            }
        }
    }

    __syncthreads();   // all dx accumulated

    // ---- Phase B: fully-coalesced float4 writes of [dx, -dx, 0, 0] ----
#pragma unroll
    for (int it = 0; it < 25; ++it) {
        int i = tid + it * 256;                       // RPB*100 = 6400 exact
        int row = i / 100, c4 = i - row * 100;
        f32x4 v;
        if (c4 < 25) {
            v = *reinterpret_cast<const f32x4*>(&buf[row * BUFW + c4 * 4]);
        } else if (c4 < 50) {
            f32x4 d = *reinterpret_cast<const f32x4*>(&buf[row * BUFW + c4 * 4 - DIMX]);
            v = f32x4{-d[0], -d[1], -d[2], -d[3]};
        } else {
            v = f32x4{0.f, 0.f, 0.f, 0.f};
        }
        *reinterpret_cast<f32x4*>(&out[(r0 + row) * 400 + c4 * 4]) = v;
    }
}

extern "C" void kernel_launch(void* const* d_in, const int* in_sizes, int n_in,
                              void* d_out, int out_size, void* d_ws, size_t ws_size,
                              hipStream_t stream) {
    const float* state  = (const float*)d_in[0];
    const float* Amat   = (const float*)d_in[1];
    const float* target = (const float*)d_in[2];
    float* out = (float*)d_out;
    (void)in_sizes; (void)n_in; (void)out_size;

    if (ws_size >= (size_t)(112 * 128 * sizeof(__bf16))) {
        conv_A<<<dim3(56), dim3(256), 0, stream>>>(Amat, (__bf16*)d_ws);
        ca_main<true><<<dim3(BATCH / RPB), dim3(256), 0, stream>>>(
            state, Amat, (const __bf16*)d_ws, target, out);
    } else {
        ca_main<false><<<dim3(BATCH / RPB), dim3(256), 0, stream>>>(
            state, Amat, nullptr, target, out);
    }
}

// Round 4
// 71.577 us; speedup vs baseline: 1.7594x; 1.4037x over previous
//
#include <hip/hip_runtime.h>

#define DIMX 100
#define BATCH 131072
#define BUFW 108          // f32 stride: 432 B, 16B-aligned, 2-way-free banks

typedef __bf16 bf16x8 __attribute__((ext_vector_type(8)));
typedef float  f32x4  __attribute__((ext_vector_type(4)));

// ---- kernel 1: convert A (100x100 fp32) to zero-padded bf16 [112][128] in ws ----
__global__ void conv_A(const float* __restrict__ A, __bf16* __restrict__ ws) {
    int i = blockIdx.x * 256 + threadIdx.x;          // 112*128 = 14336
    if (i < 112 * 128) {
        int j = i >> 7, k = i & 127;
        float v = (j < DIMX && k < DIMX) ? A[j * DIMX + k] : 0.0f;
        ws[i] = (__bf16)v;
    }
}

// ---- main kernel: barrier-free; each wave owns 16 rows + a private LDS tile ----
template <bool USE_WS>
__global__ __launch_bounds__(256) void ca_main(
    const float* __restrict__ state, const float* __restrict__ Amat,
    const __bf16* __restrict__ Bws, const float* __restrict__ target,
    float* __restrict__ out)
{
    __shared__ __align__(16) float buf[4][16 * BUFW];   // 27648 B, per-wave regions

    const int tid = threadIdx.x;
    const int wave = tid >> 6, lane = tid & 63;
    float* __restrict__ wbuf = buf[wave];
    const long r0 = (long)blockIdx.x * 64 + wave * 16;   // wave's first row

    // ---- Phase A: coalesced sweep of the wave's 16 rows; base = -x+u*s -> LDS ----
    // 16 rows x 25 float4 = 400 lane-items
#pragma unroll
    for (int it = 0; it < 7; ++it) {
        int i = lane + it * 64;
        if (i < 400) {
            int row = i / 25, c4 = i - row * 25, j0 = c4 * 4;
            const float* rp = state + (r0 + row) * 400;
            f32x4 x = *reinterpret_cast<const f32x4*>(rp + j0);
            f32x4 e = *reinterpret_cast<const f32x4*>(rp + DIMX + j0);
            f32x4 w = *reinterpret_cast<const f32x4*>(rp + 3 * DIMX + j0);
            f32x4 t = *reinterpret_cast<const f32x4*>(target + j0);
            f32x4 b;
#pragma unroll
            for (int q = 0; q < 4; ++q) {
                float u  = w[q] * (x[q] + e[q] - t[q]);
                float x2 = x[q] * x[q];
                float s  = x2 * __builtin_amdgcn_rcpf(1.0f + x2);
                b[q] = fmaf(u, s, -x[q]);
            }
            *reinterpret_cast<f32x4*>(&wbuf[row * BUFW + j0]) = b;
        }
    }

    // ---- A-operand frags from global x (just read by this wave -> L1-hot) ----
    const int fr = lane & 15, h = lane >> 4;
    const float* sp = state + (r0 + fr) * 400;
    bf16x8 afrag[4];
#pragma unroll
    for (int kt = 0; kt < 4; ++kt) {
        int k0 = kt * 32 + h * 8;
        bf16x8 f = {};
        if (k0 < DIMX) {
            f32x4 xa = *reinterpret_cast<const f32x4*>(sp + k0);
            f32x4 xb = *reinterpret_cast<const f32x4*>(sp + k0 + 4);
#pragma unroll
            for (int e = 0; e < 8; ++e) {
                float x = (e < 4) ? xa[e] : xb[e - 4];
                float x2 = x * x;
                float s = x2 * __builtin_amdgcn_rcpf(1.0f + x2);
                f[e] = (k0 + e < DIMX) ? (__bf16)s : (__bf16)0.0f;
            }
        }
        afrag[kt] = f;
    }

    // ---- MFMA over 7 N-tiles; epilogue: wbuf[row][j] += acc (intra-wave only) ----
#pragma unroll
    for (int n = 0; n < 7; ++n) {
        f32x4 acc = {0.f, 0.f, 0.f, 0.f};
#pragma unroll
        for (int kt = 0; kt < 4; ++kt) {
            bf16x8 bf;
            if constexpr (USE_WS) {
                bf = *reinterpret_cast<const bf16x8*>(
                    Bws + (n * 16 + fr) * 128 + kt * 32 + h * 8);
            } else {
                int jj = n * 16 + fr;
#pragma unroll
                for (int e = 0; e < 8; ++e) {
                    int k = kt * 32 + h * 8 + e;
                    float v = (jj < DIMX && k < DIMX) ? Amat[jj * DIMX + k] : 0.0f;
                    bf[e] = (__bf16)v;
                }
            }
            acc = __builtin_amdgcn_mfma_f32_16x16x32_bf16(afrag[kt], bf, acc, 0, 0, 0);
        }
        int j = n * 16 + fr;
        if (j < DIMX) {
#pragma unroll
            for (int q = 0; q < 4; ++q) {
                int row = h * 4 + q;
                wbuf[row * BUFW + j] += acc[q];
            }
        }
    }

    // ---- Phase B: perfectly-contiguous nontemporal float4 writes [dx,-dx,0,0] ----
    // 16 rows x 100 float4 = 1600 lane-items; address = base + i*16B (contiguous)
#pragma unroll
    for (int it = 0; it < 25; ++it) {
        int i = lane + it * 64;
        int row = i / 100, c4 = i - row * 100;
        f32x4 v;
        if (c4 < 25) {
            v = *reinterpret_cast<const f32x4*>(&wbuf[row * BUFW + c4 * 4]);
        } else if (c4 < 50) {
            f32x4 d = *reinterpret_cast<const f32x4*>(&wbuf[row * BUFW + c4 * 4 - DIMX]);
            v = f32x4{-d[0], -d[1], -d[2], -d[3]};
        } else {
            v = f32x4{0.f, 0.f, 0.f, 0.f};
        }
        __builtin_nontemporal_store(v,
            reinterpret_cast<f32x4*>(&out[(r0 + row) * 400 + c4 * 4]));
    }
}

extern "C" void kernel_launch(void* const* d_in, const int* in_sizes, int n_in,
                              void* d_out, int out_size, void* d_ws, size_t ws_size,
                              hipStream_t stream) {
    const float* state  = (const float*)d_in[0];
    const float* Amat   = (const float*)d_in[1];
    const float* target = (const float*)d_in[2];
    float* out = (float*)d_out;
    (void)in_sizes; (void)n_in; (void)out_size;

    if (ws_size >= (size_t)(112 * 128 * sizeof(__bf16))) {
        conv_A<<<dim3(56), dim3(256), 0, stream>>>(Amat, (__bf16*)d_ws);
        ca_main<true><<<dim3(BATCH / 64), dim3(256), 0, stream>>>(
            state, Amat, (const __bf16*)d_ws, target, out);
    } else {
        ca_main<false><<<dim3(BATCH / 64), dim3(256), 0, stream>>>(
            state, Amat, nullptr, target, out);
    }
}